// Round 4
// baseline (61.889 us; speedup 1.0000x reference)
//
#include <hip/hip_runtime.h>

#define N_COLS 3072
#define N_ROWS 3072
#define N_CH   3
#define NPIX   ((size_t)N_COLS * N_ROWS)
#define NTOT   (N_CH * NPIX)
#define RED_BLOCKS  2048
#define RED_THREADS 256
#define PAINT_THREADS 256
#define PAINT_CHUNKS  12   // 12*256 = 3072 >= max nsteps (3071)

typedef float f32x4 __attribute__((ext_vector_type(4)));  // native vec: OK for nontemporal builtins

// Kernel 1: streaming copy inp -> out (nontemporal float4) + global-max
// partials into d_ws. Every partial slot written unconditionally -> replay-safe.
__global__ __launch_bounds__(RED_THREADS)
void copy_max_kernel(const float* __restrict__ in, float* __restrict__ out,
                     float* __restrict__ partial) {
    const f32x4* in4  = (const f32x4*)in;
    f32x4*       out4 = (f32x4*)out;
    const int n4 = (int)(NTOT / 4);   // 7,077,888
    float m = -INFINITY;
    for (int i = blockIdx.x * blockDim.x + threadIdx.x; i < n4;
         i += gridDim.x * blockDim.x) {
        f32x4 v = __builtin_nontemporal_load(&in4[i]);
        __builtin_nontemporal_store(v, &out4[i]);
        m = fmaxf(m, fmaxf(fmaxf(v.x, v.y), fmaxf(v.z, v.w)));
    }
    #pragma unroll
    for (int off = 32; off > 0; off >>= 1)
        m = fmaxf(m, __shfl_down(m, off, 64));
    __shared__ float smax[RED_THREADS / 64];
    const int lane = threadIdx.x & 63;
    const int wid  = threadIdx.x >> 6;
    if (lane == 0) smax[wid] = m;
    __syncthreads();
    if (threadIdx.x == 0) {
        float r = smax[0];
        #pragma unroll
        for (int w = 1; w < RED_THREADS / 64; ++w) r = fmaxf(r, smax[w]);
        partial[blockIdx.x] = r;
    }
}

// Kernel 2: closed-form Bresenham rasterization, one thread per line step.
// For dx >= dy the x-advance fires every step (invariant 2*err > -dy), so
// step k paints (x0+sx*k, y0+sy*ck), ck = max(0, ceil((2k*dy-dx)/(2dx)));
// nsteps = max(dx,dy); the endpoint (k = nsteps) is NOT painted (reference
// sets done after the move). Mirrored for dy > dx. Verified against the
// reference recurrence on (3,2),(4,1),(1,4),(5,3),(3,3),(2,1),(1,2),(n,0).
__global__ __launch_bounds__(PAINT_THREADS)
void paint_kernel(const int* __restrict__ x_start, const int* __restrict__ x_end,
                  const int* __restrict__ y_start, const int* __restrict__ y_end,
                  const int* __restrict__ length,  const int* __restrict__ width,
                  float* __restrict__ out, const float* __restrict__ partial) {
    const int b  = blockIdx.y;
    const int x0 = x_start[b], x1 = x_end[b];
    const int y0 = y_start[b], y1 = y_end[b];

    if (x0 == x1 && y0 == y1) return;          // done0: paints nothing

    const int dx = abs(x1 - x0), dy = abs(y1 - y0);
    const int nsteps = max(dx, dy);
    if ((int)(blockIdx.x * PAINT_THREADS) >= nsteps) return;  // block-uniform

    // Wave-redundant reduction of the 2048 partials (L2-resident).
    const int lane = threadIdx.x & 63;
    float m = -INFINITY;
    for (int i = lane; i < RED_BLOCKS; i += 64) m = fmaxf(m, partial[i]);
    #pragma unroll
    for (int off = 32; off > 0; off >>= 1)
        m = fmaxf(m, __shfl_down(m, off, 64));
    const float val = __shfl(m, 0, 64);

    const int k = blockIdx.x * PAINT_THREADS + threadIdx.x;
    if (k >= nsteps) return;

    const int sx = (x0 < x1) ? 1 : -1;
    const int sy = (y0 < y1) ? 1 : -1;
    int X, Y;
    if (dx >= dy) {
        X = k;
        const int num = 2 * k * dy - dx;
        Y = (num <= 0) ? 0 : (num + 2 * dx - 1) / (2 * dx);
    } else {
        Y = k;
        const int num = 2 * k * dx - dy;
        X = (num <= 0) ? 0 : (num + 2 * dy - 1) / (2 * dy);
    }
    const int px = x0 + sx * X;
    const int py = y0 + sy * Y;

    // Clamped stamp bounds: no per-pixel divergent checks.
    const int Wv = min(width[b],  N_COLS - py);
    const int Lv = min(length[b], N_ROWS - px);
    for (int dw = 0; dw < Wv; ++dw) {
        const size_t rowp = (size_t)(py + dw) * N_ROWS + px;
        for (int dl = 0; dl < Lv; ++dl) {
            out[rowp + dl]            = val;
            out[NPIX + rowp + dl]     = val;
            out[2 * NPIX + rowp + dl] = val;
        }
    }
}

extern "C" void kernel_launch(void* const* d_in, const int* in_sizes, int n_in,
                              void* d_out, int out_size, void* d_ws, size_t ws_size,
                              hipStream_t stream) {
    const float* inp     = (const float*)d_in[0];
    const int*   x_start = (const int*)d_in[1];
    const int*   x_end   = (const int*)d_in[2];
    const int*   y_start = (const int*)d_in[3];
    const int*   y_end   = (const int*)d_in[4];
    const int*   length  = (const int*)d_in[5];
    const int*   width   = (const int*)d_in[6];
    float*       out     = (float*)d_out;
    float*       partial = (float*)d_ws;   // RED_BLOCKS floats

    copy_max_kernel<<<RED_BLOCKS, RED_THREADS, 0, stream>>>(inp, out, partial);
    dim3 pgrid(PAINT_CHUNKS, 64);
    paint_kernel<<<pgrid, PAINT_THREADS, 0, stream>>>(
        x_start, x_end, y_start, y_end, length, width, out, partial);
}

// Round 5
// 46.837 us; speedup vs baseline: 1.3214x; 1.3214x over previous
//
#include <hip/hip_runtime.h>

#define N_COLS 3072
#define N_ROWS 3072
#define N_CH   3
#define NPIX   (N_COLS * N_ROWS)          // 9,437,184  (fits int)
#define NTOT   (N_CH * NPIX)              // 28,311,552 (fits int)
#define RED_BLOCKS  1024
#define RED_THREADS 256
#define PAINT_THREADS 256
#define PAINT_CHUNKS  12   // 12*256 = 3072 >= max nsteps (3071)

// Kernel 1: copy inp -> out (float4) + global-max partials into d_ws.
// Identical to the round-2 config (measured ~6.9 TB/s). Every partial slot
// written unconditionally each call -> replay-safe.
__global__ __launch_bounds__(RED_THREADS)
void copy_max_kernel(const float* __restrict__ in, float* __restrict__ out,
                     float* __restrict__ partial) {
    const float4* in4  = (const float4*)in;
    float4*       out4 = (float4*)out;
    const int n4 = NTOT / 4;   // 7,077,888
    float m = -INFINITY;
    for (int i = blockIdx.x * blockDim.x + threadIdx.x; i < n4;
         i += gridDim.x * blockDim.x) {
        float4 v = in4[i];
        out4[i] = v;
        m = fmaxf(m, fmaxf(fmaxf(v.x, v.y), fmaxf(v.z, v.w)));
    }
    #pragma unroll
    for (int off = 32; off > 0; off >>= 1)
        m = fmaxf(m, __shfl_down(m, off, 64));
    __shared__ float smax[RED_THREADS / 64];
    const int lane = threadIdx.x & 63;
    const int wid  = threadIdx.x >> 6;
    if (lane == 0) smax[wid] = m;
    __syncthreads();
    if (threadIdx.x == 0) {
        float r = smax[0];
        #pragma unroll
        for (int w = 1; w < RED_THREADS / 64; ++w) r = fmaxf(r, smax[w]);
        partial[blockIdx.x] = r;
    }
}

// Kernel 2: closed-form Bresenham rasterization. One thread per line step;
// grid.z = channel (3 stores -> <=9 stores per thread).
// For dx >= dy the x-advance fires every step (invariant 2*err > -dy), so
// step k paints (x0+sx*k, y0+sy*ck), ck = max(0, ceil((2k*dy-dx)/(2dx)));
// nsteps = max(dx,dy); endpoint (k = nsteps) NOT painted (done-after-move).
// Mirrored for dy > dx. Verified against the reference recurrence on
// (3,2),(4,1),(1,4),(5,3),(3,3),(2,1),(1,2),(n,0).
__global__ __launch_bounds__(PAINT_THREADS)
void paint_kernel(const int* __restrict__ x_start, const int* __restrict__ x_end,
                  const int* __restrict__ y_start, const int* __restrict__ y_end,
                  const int* __restrict__ length,  const int* __restrict__ width,
                  float* __restrict__ out, const float* __restrict__ partial) {
    const int b  = blockIdx.y;
    const int x0 = x_start[b], x1 = x_end[b];
    const int y0 = y_start[b], y1 = y_end[b];

    if (x0 == x1 && y0 == y1) return;          // done0: paints nothing

    const int dx = abs(x1 - x0), dy = abs(y1 - y0);
    const int nsteps = max(dx, dy);
    if ((int)(blockIdx.x * PAINT_THREADS) >= nsteps) return;  // block-uniform

    // Wave-redundant reduction of the 1024 partials (L2-resident); must run
    // with all 64 lanes active (shfl), so it precedes the per-lane k check.
    const int lane = threadIdx.x & 63;
    float m = -INFINITY;
    #pragma unroll
    for (int i = 0; i < RED_BLOCKS / 64; ++i) m = fmaxf(m, partial[lane + i * 64]);
    #pragma unroll
    for (int off = 32; off > 0; off >>= 1)
        m = fmaxf(m, __shfl_down(m, off, 64));
    const float val = __shfl(m, 0, 64);

    const int k = blockIdx.x * PAINT_THREADS + threadIdx.x;
    if (k >= nsteps) return;

    const int sx = (x0 < x1) ? 1 : -1;
    const int sy = (y0 < y1) ? 1 : -1;
    int X, Y;
    if (dx >= dy) {
        X = k;
        const int num = 2 * k * dy - dx;
        Y = (num <= 0) ? 0 : (num + 2 * dx - 1) / (2 * dx);
    } else {
        Y = k;
        const int num = 2 * k * dx - dy;
        X = (num <= 0) ? 0 : (num + 2 * dy - 1) / (2 * dy);
    }
    const int px = x0 + sx * X;
    const int py = y0 + sy * Y;

    // Clamped stamp bounds: no per-pixel divergent checks. 32-bit offsets.
    const int Wv = min(width[b],  N_COLS - py);
    const int Lv = min(length[b], N_ROWS - px);
    float* chan = out + blockIdx.z * NPIX;
    for (int dw = 0; dw < Wv; ++dw) {
        const int rowp = (py + dw) * N_ROWS + px;
        for (int dl = 0; dl < Lv; ++dl)
            chan[rowp + dl] = val;
    }
}

extern "C" void kernel_launch(void* const* d_in, const int* in_sizes, int n_in,
                              void* d_out, int out_size, void* d_ws, size_t ws_size,
                              hipStream_t stream) {
    const float* inp     = (const float*)d_in[0];
    const int*   x_start = (const int*)d_in[1];
    const int*   x_end   = (const int*)d_in[2];
    const int*   y_start = (const int*)d_in[3];
    const int*   y_end   = (const int*)d_in[4];
    const int*   length  = (const int*)d_in[5];
    const int*   width   = (const int*)d_in[6];
    float*       out     = (float*)d_out;
    float*       partial = (float*)d_ws;   // RED_BLOCKS floats

    copy_max_kernel<<<RED_BLOCKS, RED_THREADS, 0, stream>>>(inp, out, partial);
    dim3 pgrid(PAINT_CHUNKS, 64, N_CH);
    paint_kernel<<<pgrid, PAINT_THREADS, 0, stream>>>(
        x_start, x_end, y_start, y_end, length, width, out, partial);
}